// Round 1
// baseline (366.571 us; speedup 1.0000x reference)
//
#include <hip/hip_runtime.h>
#include <hip/hip_bf16.h>

#define NN 50000   // nodes
#define HID 256    // hidden
#define NE 800000  // edges

// ---------------------------------------------------------------------------
// Kernel 1: P[n][j] = sum_k z[n][k] * W1[k + (j>=256)*256][j&255]  (+ b1[j] if j<256)
// Stored bf16, row stride 512. fp32 accumulate.
// ---------------------------------------------------------------------------
#define BM 64
#define BN 64
#define BK 32
#define LDP 68  // BM + 4 pad (keeps 16B alignment for float4 LDS ops)

__global__ __launch_bounds__(256)
void node_gemm(const float* __restrict__ z, const float* __restrict__ W1,
               const float* __restrict__ b1, unsigned short* __restrict__ P) {
    __shared__ __align__(16) float As[BK][LDP];  // transposed: As[k][m]
    __shared__ __align__(16) float Bs[BK][LDP];  // Bs[k][j]

    const int tid = threadIdx.x;
    const int bx = blockIdx.x;            // N tile: 0..7
    const int by = blockIdx.y;            // M tile: 0..781
    const int m0 = by * BM;
    const int j0 = bx * BN;
    const int boff  = (j0 >= HID) ? HID : 0;    // which half of W1
    const int jcol0 = j0 & (HID - 1);           // column within half

    const int tm = tid >> 4;              // 0..15
    const int tn = tid & 15;              // 0..15

    // A-load: rows ra, ra+32 ; 4 floats at ca4
    const int ra  = tid >> 3;             // 0..31
    const int ca4 = (tid & 7) * 4;        // 0..28
    // B-load: k rows rb, rb+16 ; 4 floats at cb4
    const int rb  = tid >> 4;             // 0..15
    const int cb4 = (tid & 15) * 4;       // 0..60

    float acc[4][4] = {};

    for (int k0 = 0; k0 < HID; k0 += BK) {
        // ---- stage A (transpose into As[k][m]) ----
        #pragma unroll
        for (int half = 0; half < 2; ++half) {
            const int r  = ra + half * 32;
            const int gm = m0 + r;
            float4 v = make_float4(0.f, 0.f, 0.f, 0.f);
            if (gm < NN)
                v = *(const float4*)(z + (size_t)gm * HID + k0 + ca4);
            As[ca4 + 0][r] = v.x;
            As[ca4 + 1][r] = v.y;
            As[ca4 + 2][r] = v.z;
            As[ca4 + 3][r] = v.w;
        }
        // ---- stage B ----
        #pragma unroll
        for (int half = 0; half < 2; ++half) {
            const int k = rb + half * 16;
            const float4 v = *(const float4*)(W1 + (size_t)(k0 + k + boff) * HID + jcol0 + cb4);
            *(float4*)&Bs[k][cb4] = v;
        }
        __syncthreads();

        #pragma unroll
        for (int k = 0; k < BK; ++k) {
            const float4 av = *(const float4*)&As[k][tm * 4];
            const float4 bv = *(const float4*)&Bs[k][tn * 4];
            const float aa[4] = {av.x, av.y, av.z, av.w};
            const float bb[4] = {bv.x, bv.y, bv.z, bv.w};
            #pragma unroll
            for (int i = 0; i < 4; ++i)
                #pragma unroll
                for (int j = 0; j < 4; ++j)
                    acc[i][j] = fmaf(aa[i], bb[j], acc[i][j]);
        }
        __syncthreads();
    }

    // ---- epilogue: +b1 (top half only), cvt bf16, packed 8B stores ----
    #pragma unroll
    for (int i = 0; i < 4; ++i) {
        const int gm = m0 + tm * 4 + i;
        if (gm < NN) {
            ushort4 pk;
            float v0 = acc[i][0], v1 = acc[i][1], v2 = acc[i][2], v3 = acc[i][3];
            if (boff == 0) {
                const int jc = jcol0 + tn * 4;
                v0 += b1[jc + 0];
                v1 += b1[jc + 1];
                v2 += b1[jc + 2];
                v3 += b1[jc + 3];
            }
            __hip_bfloat16 h0 = __float2bfloat16(v0);
            __hip_bfloat16 h1 = __float2bfloat16(v1);
            __hip_bfloat16 h2 = __float2bfloat16(v2);
            __hip_bfloat16 h3 = __float2bfloat16(v3);
            pk.x = *reinterpret_cast<unsigned short*>(&h0);
            pk.y = *reinterpret_cast<unsigned short*>(&h1);
            pk.z = *reinterpret_cast<unsigned short*>(&h2);
            pk.w = *reinterpret_cast<unsigned short*>(&h3);
            *(ushort4*)(P + (size_t)gm * 512 + j0 + tn * 4) = pk;
        }
    }
}

// ---------------------------------------------------------------------------
// Kernel 2: out[e] = b2 + sum_h relu(P[src][h] + P[dst][256+h]) * W2[h]
// 16 lanes per edge (4 edges/wave), 16 features/lane, W2 cached in regs.
// ---------------------------------------------------------------------------
__device__ __forceinline__ void proc_pair(unsigned int ua, unsigned int ub,
                                          float w0, float w1, float& s) {
    const float a0 = __uint_as_float(ua << 16);
    const float a1 = __uint_as_float(ua & 0xffff0000u);
    const float b0 = __uint_as_float(ub << 16);
    const float b1 = __uint_as_float(ub & 0xffff0000u);
    const float x0 = fmaxf(a0 + b0, 0.f);
    const float x1 = fmaxf(a1 + b1, 0.f);
    s = fmaf(x0, w0, s);
    s = fmaf(x1, w1, s);
}

__global__ __launch_bounds__(256)
void edge_kernel(const int* __restrict__ ei, const unsigned short* __restrict__ P,
                 const float* __restrict__ W2, const float* __restrict__ b2,
                 float* __restrict__ out) {
    const int lane = threadIdx.x & 63;
    const int sub  = lane >> 4;          // edge within wave (0..3)
    const int l16  = lane & 15;
    const int h0   = l16 * 16;           // this lane's 16 features

    // W2 slice + b2 held in registers for the whole grid-stride loop
    float w[16];
    #pragma unroll
    for (int i = 0; i < 16; i += 4) {
        const float4 v = *(const float4*)(W2 + h0 + i);
        w[i] = v.x; w[i + 1] = v.y; w[i + 2] = v.z; w[i + 3] = v.w;
    }
    const float bias2 = b2[0];

    const int gwave  = (blockIdx.x * blockDim.x + threadIdx.x) >> 6;
    const int nwaves = (gridDim.x * blockDim.x) >> 6;
    const int ngroups = NE >> 2;         // 4 edges per wave

    for (int g = gwave; g < ngroups; g += nwaves) {
        const int e   = g * 4 + sub;
        const int src = ei[e];
        const int dst = ei[NE + e];

        const unsigned short* pa = P + (size_t)src * 512 + h0;        // top half
        const unsigned short* pb = P + (size_t)dst * 512 + 256 + h0;  // bottom half
        const uint4 ta0 = *(const uint4*)(pa);
        const uint4 ta1 = *(const uint4*)(pa + 8);
        const uint4 tb0 = *(const uint4*)(pb);
        const uint4 tb1 = *(const uint4*)(pb + 8);

        float s = 0.f;
        proc_pair(ta0.x, tb0.x, w[0],  w[1],  s);
        proc_pair(ta0.y, tb0.y, w[2],  w[3],  s);
        proc_pair(ta0.z, tb0.z, w[4],  w[5],  s);
        proc_pair(ta0.w, tb0.w, w[6],  w[7],  s);
        proc_pair(ta1.x, tb1.x, w[8],  w[9],  s);
        proc_pair(ta1.y, tb1.y, w[10], w[11], s);
        proc_pair(ta1.z, tb1.z, w[12], w[13], s);
        proc_pair(ta1.w, tb1.w, w[14], w[15], s);

        // reduce across the 16-lane group
        s += __shfl_xor(s, 1);
        s += __shfl_xor(s, 2);
        s += __shfl_xor(s, 4);
        s += __shfl_xor(s, 8);
        if (l16 == 0) out[e] = s + bias2;
    }
}

// ---------------------------------------------------------------------------
extern "C" void kernel_launch(void* const* d_in, const int* in_sizes, int n_in,
                              void* d_out, int out_size, void* d_ws, size_t ws_size,
                              hipStream_t stream) {
    const float* z  = (const float*)d_in[0];
    const int*   ei = (const int*)d_in[1];
    const float* W1 = (const float*)d_in[2];
    const float* b1 = (const float*)d_in[3];
    const float* W2 = (const float*)d_in[4];
    const float* b2 = (const float*)d_in[5];
    float* out = (float*)d_out;
    unsigned short* P = (unsigned short*)d_ws;   // [NN][512] bf16

    dim3 g1(8, (NN + BM - 1) / BM);
    node_gemm<<<g1, 256, 0, stream>>>(z, W1, b1, P);

    edge_kernel<<<2048, 256, 0, stream>>>(ei, P, W2, b2, out);
}

// Round 2
// 284.564 us; speedup vs baseline: 1.2882x; 1.2882x over previous
//
#include <hip/hip_runtime.h>
#include <hip/hip_bf16.h>

#define NN 50000   // nodes
#define HID 256    // hidden
#define NE 800000  // edges

typedef unsigned short u16;
typedef __attribute__((ext_vector_type(8))) short short8v;  // 8 bf16 = 4 VGPRs
typedef __attribute__((ext_vector_type(4))) float f32x4;

__device__ __forceinline__ u16 f2bf(float v) {
    __hip_bfloat16 h = __float2bfloat16(v);
    return *reinterpret_cast<u16*>(&h);
}

// ---------------------------------------------------------------------------
// Prep: W1b[kbg][j][kk] bf16, kbg in [0,32), j in [0,512), kk in [0,8).
// B[k][j] = W1[k + (j>=256)*256][j&255], k = kbg*8+kk.
// This is exactly the MFMA B-fragment feed order -> GEMM B-staging is a
// contiguous 16B-per-thread copy.
// ---------------------------------------------------------------------------
__global__ __launch_bounds__(256)
void prep_w1b(const float* __restrict__ W1, u16* __restrict__ W1b) {
    const int idx = blockIdx.x * 256 + threadIdx.x;   // 32*512 = 16384
    if (idx >= 32 * 512) return;
    const int kbg  = idx >> 9;
    const int j    = idx & 511;
    const int row0 = (j >= HID) ? HID : 0;
    const int col  = j & (HID - 1);
    u16 o[8];
    #pragma unroll
    for (int kk = 0; kk < 8; ++kk) {
        const int k = kbg * 8 + kk;
        o[kk] = f2bf(W1[(size_t)(row0 + k) * HID + col]);
    }
    *(uint4*)(W1b + (size_t)idx * 8) = *(uint4*)o;
}

// ---------------------------------------------------------------------------
// Kernel 1 (MFMA): P[M=50000, N=512] = A[M,256] x B[256,512]  (+b1 on j<256)
// 128x128 tile, 4 waves, each wave 64x64 via 4x4 mfma_f32_16x16x32_bf16.
// A staged fp32->bf16 into LDS [kb][r][8]; B staged from W1b (already in
// fragment layout). Epilogue through LDS for coalesced 16B stores.
// ---------------------------------------------------------------------------
#define BM 128
#define BN 128
#define BK 32
#define LDE 136   // epilogue row stride in u16 (272B = 17*16B, keeps 16B align)

__global__ __launch_bounds__(256)
void node_gemm(const float* __restrict__ z, const u16* __restrict__ W1b,
               const float* __restrict__ b1, u16* __restrict__ P) {
    // staging: A = lds[0..4096) u16  [kb][r 0..127][kk 0..7]
    //          B = lds[4096..8192)   [kb][j 0..127][kk 0..7]
    // epilogue reuses lds[0..17408) as [128][LDE]
    __shared__ __align__(16) u16 lds[BM * LDE];

    const int tid  = threadIdx.x;
    const int lane = tid & 63;
    const int wid  = tid >> 6;
    const int wr   = wid >> 1;            // wave row (0..1)
    const int wc   = wid & 1;             // wave col (0..1)
    const int m0 = blockIdx.y * BM;
    const int j0 = blockIdx.x * BN;       // 0,128,256,384

    const int l16 = lane & 15;
    const int l4  = lane >> 4;            // k-block 0..3

    // A-stage addressing: 4 float4 per thread
    const int ar  = tid >> 3;             // base row within 32-row group
    const int ac4 = (tid & 7) * 4;        // k offset 0..28
    const int akb = ac4 >> 3;             // k-block of this float4
    const int akk = ac4 & 7;              // 0 or 4

    f32x4 acc[4][4] = {};

    for (int k0 = 0; k0 < HID; k0 += BK) {
        // ---- issue global loads (regs) ----
        float4 av[4];
        #pragma unroll
        for (int q = 0; q < 4; ++q) {
            const int r  = q * 32 + ar;
            const int gm = m0 + r;
            av[q] = (gm < NN) ? *(const float4*)(z + (size_t)gm * HID + k0 + ac4)
                              : make_float4(0.f, 0.f, 0.f, 0.f);
        }
        uint4 bv[2];
        #pragma unroll
        for (int h = 0; h < 2; ++h) {
            const int kb = h * 2 + (tid >> 7);
            const int j  = tid & 127;
            bv[h] = *(const uint4*)(W1b + ((size_t)((k0 >> 3) + kb) * 512 + j0 + j) * 8);
        }
        __syncthreads();   // previous iter's frag reads complete before overwrite
        // ---- LDS writes ----
        #pragma unroll
        for (int q = 0; q < 4; ++q) {
            const int r = q * 32 + ar;
            u16 pk[4] = { f2bf(av[q].x), f2bf(av[q].y), f2bf(av[q].z), f2bf(av[q].w) };
            *(uint2*)&lds[akb * (BM * 8) + r * 8 + akk] = *(uint2*)pk;
        }
        #pragma unroll
        for (int h = 0; h < 2; ++h) {
            const int kb = h * 2 + (tid >> 7);
            const int j  = tid & 127;
            *(uint4*)&lds[4096 + kb * (BN * 8) + j * 8] = bv[h];
        }
        __syncthreads();
        // ---- fragments + MFMA ----
        short8v a[4], b[4];
        #pragma unroll
        for (int mi = 0; mi < 4; ++mi)
            a[mi] = *(short8v*)&lds[l4 * (BM * 8) + (wr * 64 + mi * 16 + l16) * 8];
        #pragma unroll
        for (int ni = 0; ni < 4; ++ni)
            b[ni] = *(short8v*)&lds[4096 + l4 * (BN * 8) + (wc * 64 + ni * 16 + l16) * 8];
        #pragma unroll
        for (int mi = 0; mi < 4; ++mi)
            #pragma unroll
            for (int ni = 0; ni < 4; ++ni)
                acc[mi][ni] = __builtin_amdgcn_mfma_f32_16x16x32_bf16(
                    a[mi], b[ni], acc[mi][ni], 0, 0, 0);
    }

    // ---- epilogue: +b1, bf16, LDS roundtrip, coalesced stores ----
    float bvals[4];
    #pragma unroll
    for (int ni = 0; ni < 4; ++ni) {
        const int col = j0 + wc * 64 + ni * 16 + l16;
        bvals[ni] = (col < HID) ? b1[col] : 0.f;
    }
    __syncthreads();   // all frag reads done before epilogue overwrite
    #pragma unroll
    for (int mi = 0; mi < 4; ++mi) {
        const int rbase = wr * 64 + mi * 16 + l4 * 4;
        #pragma unroll
        for (int ni = 0; ni < 4; ++ni) {
            const int c = wc * 64 + ni * 16 + l16;
            #pragma unroll
            for (int r = 0; r < 4; ++r)
                lds[(rbase + r) * LDE + c] = f2bf(acc[mi][ni][r] + bvals[ni]);
        }
    }
    __syncthreads();
    #pragma unroll
    for (int it = 0; it < 8; ++it) {
        const int flat = it * 256 + tid;
        const int row  = flat >> 4;
        const int g    = flat & 15;
        const int gm   = m0 + row;
        if (gm < NN)
            *(uint4*)(P + (size_t)gm * 512 + j0 + g * 8) = *(uint4*)&lds[row * LDE + g * 8];
    }
}

// ---------------------------------------------------------------------------
// Kernel 2: out[e] = b2 + sum_h relu(P[src][h] + P[dst][256+h]) * W2[h]
// 16 lanes per edge (4 edges/wave), 16 features/lane, W2 cached in regs.
// ---------------------------------------------------------------------------
__device__ __forceinline__ void proc_pair(unsigned int ua, unsigned int ub,
                                          float w0, float w1, float& s) {
    const float a0 = __uint_as_float(ua << 16);
    const float a1 = __uint_as_float(ua & 0xffff0000u);
    const float b0 = __uint_as_float(ub << 16);
    const float b1 = __uint_as_float(ub & 0xffff0000u);
    const float x0 = fmaxf(a0 + b0, 0.f);
    const float x1 = fmaxf(a1 + b1, 0.f);
    s = fmaf(x0, w0, s);
    s = fmaf(x1, w1, s);
}

__global__ __launch_bounds__(256)
void edge_kernel(const int* __restrict__ ei, const u16* __restrict__ P,
                 const float* __restrict__ W2, const float* __restrict__ b2,
                 float* __restrict__ out) {
    const int lane = threadIdx.x & 63;
    const int sub  = lane >> 4;          // edge within wave (0..3)
    const int l16  = lane & 15;
    const int h0   = l16 * 16;           // this lane's 16 features

    float w[16];
    #pragma unroll
    for (int i = 0; i < 16; i += 4) {
        const float4 v = *(const float4*)(W2 + h0 + i);
        w[i] = v.x; w[i + 1] = v.y; w[i + 2] = v.z; w[i + 3] = v.w;
    }
    const float bias2 = b2[0];

    const int gwave   = (blockIdx.x * blockDim.x + threadIdx.x) >> 6;
    const int nwaves  = (gridDim.x * blockDim.x) >> 6;
    const int ngroups = NE >> 2;

    for (int g = gwave; g < ngroups; g += nwaves) {
        const int e   = g * 4 + sub;
        const int src = ei[e];
        const int dst = ei[NE + e];

        const u16* pa = P + (size_t)src * 512 + h0;
        const u16* pb = P + (size_t)dst * 512 + 256 + h0;
        const uint4 ta0 = *(const uint4*)(pa);
        const uint4 ta1 = *(const uint4*)(pa + 8);
        const uint4 tb0 = *(const uint4*)(pb);
        const uint4 tb1 = *(const uint4*)(pb + 8);

        float s = 0.f;
        proc_pair(ta0.x, tb0.x, w[0],  w[1],  s);
        proc_pair(ta0.y, tb0.y, w[2],  w[3],  s);
        proc_pair(ta0.z, tb0.z, w[4],  w[5],  s);
        proc_pair(ta0.w, tb0.w, w[6],  w[7],  s);
        proc_pair(ta1.x, tb1.x, w[8],  w[9],  s);
        proc_pair(ta1.y, tb1.y, w[10], w[11], s);
        proc_pair(ta1.z, tb1.z, w[12], w[13], s);
        proc_pair(ta1.w, tb1.w, w[14], w[15], s);

        s += __shfl_xor(s, 1);
        s += __shfl_xor(s, 2);
        s += __shfl_xor(s, 4);
        s += __shfl_xor(s, 8);
        if (l16 == 0) out[e] = s + bias2;
    }
}

// ---------------------------------------------------------------------------
extern "C" void kernel_launch(void* const* d_in, const int* in_sizes, int n_in,
                              void* d_out, int out_size, void* d_ws, size_t ws_size,
                              hipStream_t stream) {
    const float* z  = (const float*)d_in[0];
    const int*   ei = (const int*)d_in[1];
    const float* W1 = (const float*)d_in[2];
    const float* b1 = (const float*)d_in[3];
    const float* W2 = (const float*)d_in[4];
    const float* b2 = (const float*)d_in[5];
    float* out = (float*)d_out;

    u16* W1b = (u16*)d_ws;                 // 256 KB, fragment-layout bf16 B
    u16* P   = (u16*)d_ws + 131072;        // [NN][512] bf16 partials

    prep_w1b<<<64, 256, 0, stream>>>(W1, W1b);

    dim3 g1(4, (NN + BM - 1) / BM);
    node_gemm<<<g1, 256, 0, stream>>>(z, W1b, b1, P);

    edge_kernel<<<2048, 256, 0, stream>>>(ei, P, W2, b2, out);
}